// Round 1
// baseline (26994.946 us; speedup 1.0000x reference)
//
#include <hip/hip_runtime.h>
#include <hip/hip_bf16.h>
#include <math.h>

#define B_      32
#define NTOK    197
#define NPATCH  196
#define D_      768
#define DFF     3072
#define L_      12
#define NH      12
#define HD      64
#define NCLS    5

// ---------------------------------------------------------------------------
// tok[b,0,d] = cls[d] + pos[0,d]
__global__ __launch_bounds__(256) void cls_pos_kernel(
    const float* __restrict__ cls, const float* __restrict__ pos,
    float* __restrict__ tok) {
  int i = blockIdx.x * 256 + threadIdx.x;
  if (i < B_ * D_) {
    int b = i / D_, d = i % D_;
    tok[(size_t)b * NTOK * D_ + d] = cls[d] + pos[d];
  }
}

// ---------------------------------------------------------------------------
// patch conv: one block per (b, patch). Stage the 3*16*16=768 input patch in
// LDS, each thread dots it against weight rows. tok[b,1+n,d] = conv + cb + pos.
__global__ __launch_bounds__(256) void patch_embed_kernel(
    const float* __restrict__ x, const float* __restrict__ w,
    const float* __restrict__ cb, const float* __restrict__ pos,
    float* __restrict__ tok) {
  int blk = blockIdx.x;
  int b = blk / NPATCH, n = blk % NPATCH;
  int ph = n / 14, pw = n % 14;
  __shared__ float patch[768];
  int tid = threadIdx.x;
  for (int e = tid; e < 768; e += 256) {
    int c = e >> 8;            // /256
    int r = e & 255;
    int kh = r >> 4, kw = r & 15;
    patch[e] = x[(((size_t)b * 3 + c) * 224 + (ph * 16 + kh)) * 224 + (pw * 16 + kw)];
  }
  __syncthreads();
  for (int d = tid; d < D_; d += 256) {
    const float* wr = w + (size_t)d * 768;
    float s = 0.f;
#pragma unroll 8
    for (int i = 0; i < 768; i++) s += patch[i] * wr[i];
    tok[((size_t)b * NTOK + 1 + n) * D_ + d] = s + cb[d] + pos[(size_t)(1 + n) * D_ + d];
  }
}

// ---------------------------------------------------------------------------
// row layernorm, 768 cols, block=256, one row per block.
__global__ __launch_bounds__(256) void ln_kernel(
    const float* __restrict__ in, float* __restrict__ out,
    const float* __restrict__ g, const float* __restrict__ bt,
    long rs_in, long rs_out) {
  int row = blockIdx.x;
  const float* xr = in + (size_t)row * rs_in;
  float* yr = out + (size_t)row * rs_out;
  int tid = threadIdx.x;
  float v0 = xr[tid], v1 = xr[tid + 256], v2 = xr[tid + 512];
  float s = v0 + v1 + v2;
#pragma unroll
  for (int off = 32; off; off >>= 1) s += __shfl_xor(s, off);
  __shared__ float red1[4], red2[4];
  int wid = tid >> 6, lane = tid & 63;
  if (lane == 0) red1[wid] = s;
  __syncthreads();
  float mean = (red1[0] + red1[1] + red1[2] + red1[3]) * (1.f / 768.f);
  float d0 = v0 - mean, d1 = v1 - mean, d2 = v2 - mean;
  float s2 = d0 * d0 + d1 * d1 + d2 * d2;
#pragma unroll
  for (int off = 32; off; off >>= 1) s2 += __shfl_xor(s2, off);
  if (lane == 0) red2[wid] = s2;
  __syncthreads();
  float var = (red2[0] + red2[1] + red2[2] + red2[3]) * (1.f / 768.f);
  float rstd = rsqrtf(var + 1e-5f);
  yr[tid]       = d0 * rstd * g[tid]       + bt[tid];
  yr[tid + 256] = d1 * rstd * g[tid + 256] + bt[tid + 256];
  yr[tid + 512] = d2 * rstd * g[tid + 512] + bt[tid + 512];
}

// ---------------------------------------------------------------------------
// C[M,N] = A[M,K] @ W[K,N] + bias (+res) (gelu). 64x64 tile, BK=16, 4x4/thread.
template <bool RES, bool GELU>
__global__ __launch_bounds__(256) void gemm_kernel(
    const float* __restrict__ A, const float* __restrict__ W,
    const float* __restrict__ bias, const float* __restrict__ res,
    float* __restrict__ C, int M, int N, int K) {
  __shared__ float As[64][17];   // [m][k], padded
  __shared__ float Bs[16][64];   // [k][n]
  int tid = threadIdx.x;
  int tx = tid & 15, ty = tid >> 4;
  int nbase = blockIdx.x * 64;
  int mbase = blockIdx.y * 64;
  float acc[4][4] = {};
  for (int k0 = 0; k0 < K; k0 += 16) {
#pragma unroll
    for (int e = 0; e < 4; e++) {
      int idx = e * 256 + tid;         // 64x16 A tile, k fastest (coalesced 64B rows)
      int m = idx >> 4, k = idx & 15;
      int gm = mbase + m;
      As[m][k] = (gm < M) ? A[(size_t)gm * K + k0 + k] : 0.f;
    }
#pragma unroll
    for (int e = 0; e < 4; e++) {
      int idx = e * 256 + tid;         // 16x64 B tile, n fastest (coalesced)
      int k = idx >> 6, n = idx & 63;
      Bs[k][n] = W[(size_t)(k0 + k) * N + nbase + n];
    }
    __syncthreads();
#pragma unroll
    for (int k = 0; k < 16; k++) {
      float a[4], b[4];
#pragma unroll
      for (int i = 0; i < 4; i++) a[i] = As[ty * 4 + i][k];
#pragma unroll
      for (int j = 0; j < 4; j++) b[j] = Bs[k][tx * 4 + j];
#pragma unroll
      for (int i = 0; i < 4; i++)
#pragma unroll
        for (int j = 0; j < 4; j++) acc[i][j] += a[i] * b[j];
    }
    __syncthreads();
  }
#pragma unroll
  for (int i = 0; i < 4; i++) {
    int gm = mbase + ty * 4 + i;
    if (gm >= M) continue;
#pragma unroll
    for (int j = 0; j < 4; j++) {
      int gn = nbase + tx * 4 + j;
      float c = acc[i][j] + bias[gn];
      if (RES) c += res[(size_t)gm * N + gn];
      if (GELU) c = 0.5f * c * (1.f + erff(c * 0.70710678118654752f));
      C[(size_t)gm * N + gn] = c;
    }
  }
}

// ---------------------------------------------------------------------------
// fused attention: one wave per (b, h, q). qkv row layout: [q(768)|k(768)|v(768)],
// head h occupies cols h*64..h*64+63 of each 768 segment.
__global__ __launch_bounds__(64) void attn_kernel(
    const float* __restrict__ qkv, float* __restrict__ o) {
  int blk = blockIdx.x;
  int q_idx = blk % NTOK;
  int h = (blk / NTOK) % NH;
  int b = blk / (NTOK * NH);
  int lane = threadIdx.x;
  const float* base = qkv + (size_t)b * NTOK * 3 * D_;
  __shared__ float qs[64];
  __shared__ float sc[224];
  qs[lane] = base[(size_t)q_idx * 3 * D_ + h * HD + lane];
  __syncthreads();
  const float scale = 0.125f;  // 64^-0.5
  for (int kk = lane; kk < NTOK; kk += 64) {
    const float* krow = base + (size_t)kk * 3 * D_ + D_ + h * HD;
    float s = 0.f;
#pragma unroll 8
    for (int i = 0; i < HD; i++) s += qs[i] * krow[i];
    sc[kk] = s * scale;
  }
  __syncthreads();
  float m = -1e30f;
  for (int kk = lane; kk < NTOK; kk += 64) m = fmaxf(m, sc[kk]);
#pragma unroll
  for (int off = 32; off; off >>= 1) m = fmaxf(m, __shfl_xor(m, off));
  float sum = 0.f;
  for (int kk = lane; kk < NTOK; kk += 64) {
    float e = __expf(sc[kk] - m);
    sc[kk] = e;
    sum += e;
  }
#pragma unroll
  for (int off = 32; off; off >>= 1) sum += __shfl_xor(sum, off);
  __syncthreads();
  float inv = 1.f / sum;
  float acc = 0.f;
  for (int kk = 0; kk < NTOK; kk++) {
    acc += sc[kk] * base[(size_t)kk * 3 * D_ + 2 * D_ + h * HD + lane];
  }
  o[((size_t)b * NTOK + q_idx) * D_ + h * HD + lane] = acc * inv;
}

// ---------------------------------------------------------------------------
// head: out[b,j] = y[b,:] @ head_w[:,j] + head_b[j]; one wave per b.
__global__ __launch_bounds__(64) void head_kernel(
    const float* __restrict__ y, const float* __restrict__ hw,
    const float* __restrict__ hb, float* __restrict__ out) {
  int b = blockIdx.x;
  const float* yr = y + (size_t)b * D_;
  int lane = threadIdx.x;
  for (int j = 0; j < NCLS; j++) {
    float s = 0.f;
    for (int d = lane; d < D_; d += 64) s += yr[d] * hw[(size_t)d * NCLS + j];
#pragma unroll
    for (int off = 32; off; off >>= 1) s += __shfl_xor(s, off);
    if (lane == 0) out[b * NCLS + j] = s + hb[j];
  }
}

// ---------------------------------------------------------------------------
extern "C" void kernel_launch(void* const* d_in, const int* in_sizes, int n_in,
                              void* d_out, int out_size, void* d_ws, size_t ws_size,
                              hipStream_t stream) {
  const float* x        = (const float*)d_in[0];
  const float* conv_w   = (const float*)d_in[1];
  const float* conv_b   = (const float*)d_in[2];
  const float* cls_tok  = (const float*)d_in[3];
  const float* pos_emb  = (const float*)d_in[4];
  const float* ln1_g    = (const float*)d_in[5];
  const float* ln1_b    = (const float*)d_in[6];
  const float* qkv_w    = (const float*)d_in[7];
  const float* qkv_b    = (const float*)d_in[8];
  const float* proj_w   = (const float*)d_in[9];
  const float* proj_b   = (const float*)d_in[10];
  const float* ln2_g    = (const float*)d_in[11];
  const float* ln2_b    = (const float*)d_in[12];
  const float* fc1_w    = (const float*)d_in[13];
  const float* fc1_b    = (const float*)d_in[14];
  const float* fc2_w    = (const float*)d_in[15];
  const float* fc2_b    = (const float*)d_in[16];
  const float* norm_g   = (const float*)d_in[17];
  const float* norm_b   = (const float*)d_in[18];
  const float* head_w   = (const float*)d_in[19];
  const float* head_b   = (const float*)d_in[20];
  float* out = (float*)d_out;

  const int M = B_ * NTOK;  // 6304
  float* tok  = (float*)d_ws;
  float* y    = tok + (size_t)M * D_;
  float* R    = y + (size_t)M * D_;
  float* qkvb = R;                          // M x 2304
  float* ob   = R + (size_t)M * 3 * D_;     // M x 768
  float* ffh  = R;                          // M x 3072 (reuses qkv+o region)

  // embed
  cls_pos_kernel<<<(B_ * D_ + 255) / 256, 256, 0, stream>>>(cls_tok, pos_emb, tok);
  patch_embed_kernel<<<B_ * NPATCH, 256, 0, stream>>>(x, conv_w, conv_b, pos_emb, tok);

  dim3 gQKV(3 * D_ / 64, (M + 63) / 64);
  dim3 gPRJ(D_ / 64, (M + 63) / 64);
  dim3 gFC1(DFF / 64, (M + 63) / 64);
  dim3 gFC2(D_ / 64, (M + 63) / 64);

  for (int l = 0; l < L_; l++) {
    const float* l1g = ln1_g + l * D_;
    const float* l1b = ln1_b + l * D_;
    const float* qw  = qkv_w + (size_t)l * D_ * 3 * D_;
    const float* qb  = qkv_b + (size_t)l * 3 * D_;
    const float* pw  = proj_w + (size_t)l * D_ * D_;
    const float* pb  = proj_b + (size_t)l * D_;
    const float* l2g = ln2_g + l * D_;
    const float* l2b = ln2_b + l * D_;
    const float* f1w = fc1_w + (size_t)l * D_ * DFF;
    const float* f1b = fc1_b + (size_t)l * DFF;
    const float* f2w = fc2_w + (size_t)l * DFF * D_;
    const float* f2b = fc2_b + (size_t)l * D_;

    ln_kernel<<<M, 256, 0, stream>>>(tok, y, l1g, l1b, D_, D_);
    gemm_kernel<false, false><<<gQKV, 256, 0, stream>>>(y, qw, qb, nullptr, qkvb, M, 3 * D_, D_);
    attn_kernel<<<B_ * NH * NTOK, 64, 0, stream>>>(qkvb, ob);
    gemm_kernel<true, false><<<gPRJ, 256, 0, stream>>>(ob, pw, pb, tok, tok, M, D_, D_);
    ln_kernel<<<M, 256, 0, stream>>>(tok, y, l2g, l2b, D_, D_);
    gemm_kernel<false, true><<<gFC1, 256, 0, stream>>>(y, f1w, f1b, nullptr, ffh, M, DFF, D_);
    gemm_kernel<true, false><<<gFC2, 256, 0, stream>>>(ffh, f2w, f2b, tok, tok, M, D_, DFF);
  }

  // final LN on token 0 of each batch, then head
  ln_kernel<<<B_, 256, 0, stream>>>(tok, y, norm_g, norm_b, (long)NTOK * D_, D_);
  head_kernel<<<B_, 64, 0, stream>>>(y, head_w, head_b, out);
}

// Round 2
// 10944.650 us; speedup vs baseline: 2.4665x; 2.4665x over previous
//
#include <hip/hip_runtime.h>
#include <hip/hip_bf16.h>
#include <math.h>

#define B_      32
#define NTOK    197
#define NPATCH  196
#define D_      768
#define DFF     3072
#define L_      12
#define NH      12
#define HD      64
#define NCLS    5
#define MTOK    (B_ * NTOK)      // 6304
#define MPAD    6400             // padded rows for bf16 activation buffers
#define MPATCH  (B_ * NPATCH)    // 6272

typedef __attribute__((ext_vector_type(8))) short short8;
typedef __attribute__((ext_vector_type(4))) float floatx4;

static __device__ inline short f2bf(float f) {
  __hip_bfloat16 h = __float2bfloat16(f);
  short s; __builtin_memcpy(&s, &h, 2); return s;
}

// ---------------------------------------------------------------------------
// tok[b,0,d] = cls[d] + pos[0,d]
__global__ __launch_bounds__(256) void cls_pos_kernel(
    const float* __restrict__ cls, const float* __restrict__ pos,
    float* __restrict__ tok) {
  int i = blockIdx.x * 256 + threadIdx.x;
  if (i < B_ * D_) {
    int b = i / D_, d = i % D_;
    tok[(size_t)b * NTOK * D_ + d] = cls[d] + pos[d];
  }
}

// ---------------------------------------------------------------------------
// elementwise fp32 -> bf16 convert (conv_w, already [N=768][K=768] layout)
__global__ __launch_bounds__(256) void cvt_kernel(
    const float* __restrict__ src, short* __restrict__ dst, int n) {
  int i = blockIdx.x * 256 + threadIdx.x;
  if (i < n) dst[i] = f2bf(src[i]);
}

// ---------------------------------------------------------------------------
// W[K,N] fp32 -> Wt[N,K] bf16, 32x32 LDS tiles. K,N multiples of 32.
__global__ __launch_bounds__(256) void wconv_kernel(
    const float* __restrict__ W, short* __restrict__ Wt, int K, int N) {
  __shared__ float t[32][33];
  int n0 = blockIdx.x * 32, k0 = blockIdx.y * 32;
  int tid = threadIdx.x;
#pragma unroll
  for (int q = 0; q < 4; q++) {
    int e = q * 256 + tid;
    int rk = e >> 5, cn = e & 31;
    t[rk][cn] = W[(size_t)(k0 + rk) * N + n0 + cn];
  }
  __syncthreads();
#pragma unroll
  for (int q = 0; q < 4; q++) {
    int e = q * 256 + tid;
    int rn = e >> 5, ck = e & 31;
    Wt[(size_t)(n0 + rn) * K + k0 + ck] = f2bf(t[ck][rn]);
  }
}

// ---------------------------------------------------------------------------
// im2col: Abf[b*196+n][c*256+kh*16+kw] = bf16(x[b,c,ph*16+kh,pw*16+kw])
__global__ __launch_bounds__(256) void im2col_kernel(
    const float* __restrict__ x, short* __restrict__ Abf) {
  int i = blockIdx.x * 256 + threadIdx.x;
  if (i >= MPATCH * D_) return;
  int row = i / D_, col = i % D_;
  int b = row / NPATCH, n = row % NPATCH;
  int ph = n / 14, pw = n % 14;
  int c = col >> 8, r = col & 255;
  int kh = r >> 4, kw = r & 15;
  Abf[i] = f2bf(x[(((size_t)b * 3 + c) * 224 + (ph * 16 + kh)) * 224 + (pw * 16 + kw)]);
}

// ---------------------------------------------------------------------------
// scatter patch gemm output into tok with pos add
__global__ __launch_bounds__(256) void patch_scatter_kernel(
    const float* __restrict__ po, const float* __restrict__ pos,
    float* __restrict__ tok) {
  int i = blockIdx.x * 256 + threadIdx.x;
  if (i >= MPATCH * D_) return;
  int row = i / D_, col = i % D_;
  int b = row / NPATCH, n = row % NPATCH;
  tok[((size_t)b * NTOK + 1 + n) * D_ + col] = po[i] + pos[(size_t)(1 + n) * D_ + col];
}

// ---------------------------------------------------------------------------
// row layernorm, 768 cols, block=256, one row per block. OBF: bf16 output.
template <bool OBF>
__global__ __launch_bounds__(256) void ln_kernel(
    const float* __restrict__ in, void* __restrict__ out,
    const float* __restrict__ g, const float* __restrict__ bt,
    long rs_in) {
  int row = blockIdx.x;
  const float* xr = in + (size_t)row * rs_in;
  int tid = threadIdx.x;
  float v0 = xr[tid], v1 = xr[tid + 256], v2 = xr[tid + 512];
  float s = v0 + v1 + v2;
#pragma unroll
  for (int off = 32; off; off >>= 1) s += __shfl_xor(s, off);
  __shared__ float red1[4], red2[4];
  int wid = tid >> 6, lane = tid & 63;
  if (lane == 0) red1[wid] = s;
  __syncthreads();
  float mean = (red1[0] + red1[1] + red1[2] + red1[3]) * (1.f / 768.f);
  float d0 = v0 - mean, d1 = v1 - mean, d2 = v2 - mean;
  float s2 = d0 * d0 + d1 * d1 + d2 * d2;
#pragma unroll
  for (int off = 32; off; off >>= 1) s2 += __shfl_xor(s2, off);
  if (lane == 0) red2[wid] = s2;
  __syncthreads();
  float var = (red2[0] + red2[1] + red2[2] + red2[3]) * (1.f / 768.f);
  float rstd = rsqrtf(var + 1e-5f);
  float o0 = d0 * rstd * g[tid]       + bt[tid];
  float o1 = d1 * rstd * g[tid + 256] + bt[tid + 256];
  float o2 = d2 * rstd * g[tid + 512] + bt[tid + 512];
  if (OBF) {
    short* yr = (short*)out + (size_t)row * D_;
    yr[tid] = f2bf(o0); yr[tid + 256] = f2bf(o1); yr[tid + 512] = f2bf(o2);
  } else {
    float* yr = (float*)out + (size_t)row * D_;
    yr[tid] = o0; yr[tid + 256] = o1; yr[tid + 512] = o2;
  }
}

// ---------------------------------------------------------------------------
// bf16 MFMA GEMM: C[M,N] = A[M,K](bf16,row-major) @ Wt[N,K](bf16,row-major)^T
// + bias (+res fp32) (gelu). 128x128 tile, BK=32, 256 thr = 4 waves (2x2),
// each wave 64x64 via 4x4 grid of 16x16x32 MFMA. global_load_lds width 16,
// XOR swizzle so fragment ds_read_b128 is bank-uniform.
template <bool OBF, bool RES, bool GELU_>
__global__ __launch_bounds__(256) void gemm_bf16_kernel(
    const short* __restrict__ A, const short* __restrict__ Wt,
    const float* __restrict__ bias, const float* __restrict__ res,
    void* __restrict__ Cout, int M, int N, int K) {
  __shared__ short As[128 * 32];
  __shared__ short Bs[128 * 32];
  const int tid = threadIdx.x;
  const int lane = tid & 63;
  const int wid = tid >> 6;               // 0..3
  const int wave_m = wid >> 1, wave_n = wid & 1;
  const int mbase = blockIdx.y * 128;
  const int nbase = blockIdx.x * 128;

  // staging: wave w loads rows [w*32, w*32+32) of each 128x32 tile,
  // two 1024B chunks of 16 rows. lane -> row w*32 + c*16 + (lane>>2),
  // fetches k-block (lane&3)^((lane>>3)&3) so LDS slot s holds global
  // block s ^ ((row>>1)&3).
  const int lrow = lane >> 2;
  const int kbg = (lane & 3) ^ ((lane >> 3) & 3);
  const short* ga0 = A + (size_t)(mbase + wid * 32 + lrow) * K + kbg * 8;
  const short* ga1 = A + (size_t)(mbase + wid * 32 + 16 + lrow) * K + kbg * 8;
  const short* gb0 = Wt + (size_t)(nbase + wid * 32 + lrow) * K + kbg * 8;
  const short* gb1 = Wt + (size_t)(nbase + wid * 32 + 16 + lrow) * K + kbg * 8;
  typedef const __attribute__((address_space(1))) unsigned* gp_t;
  typedef __attribute__((address_space(3))) unsigned* lp_t;
  lp_t lA0 = (lp_t)(void*)(As + wid * 1024);
  lp_t lA1 = (lp_t)(void*)(As + wid * 1024 + 512);
  lp_t lB0 = (lp_t)(void*)(Bs + wid * 1024);
  lp_t lB1 = (lp_t)(void*)(Bs + wid * 1024 + 512);

  floatx4 zero = {0.f, 0.f, 0.f, 0.f};
  floatx4 acc[4][4];
#pragma unroll
  for (int i = 0; i < 4; i++)
#pragma unroll
    for (int j = 0; j < 4; j++) acc[i][j] = zero;

  const int quad = lane >> 4;
  const int l15 = lane & 15;
  const int s = quad ^ ((l15 >> 1) & 3);   // LDS k-block slot for frag reads

  for (int k0 = 0; k0 < K; k0 += 32) {
    __builtin_amdgcn_global_load_lds((gp_t)(const void*)ga0, lA0, 16, 0, 0);
    __builtin_amdgcn_global_load_lds((gp_t)(const void*)ga1, lA1, 16, 0, 0);
    __builtin_amdgcn_global_load_lds((gp_t)(const void*)gb0, lB0, 16, 0, 0);
    __builtin_amdgcn_global_load_lds((gp_t)(const void*)gb1, lB1, 16, 0, 0);
    ga0 += 32; ga1 += 32; gb0 += 32; gb1 += 32;
    __syncthreads();
    short8 a[4], b[4];
#pragma unroll
    for (int i = 0; i < 4; i++) {
      int r = wave_m * 64 + i * 16 + l15;
      a[i] = *(const short8*)(As + r * 32 + s * 8);
      int c = wave_n * 64 + i * 16 + l15;
      b[i] = *(const short8*)(Bs + c * 32 + s * 8);
    }
#pragma unroll
    for (int i = 0; i < 4; i++)
#pragma unroll
      for (int j = 0; j < 4; j++)
        acc[i][j] = __builtin_amdgcn_mfma_f32_16x16x32_bf16(a[i], b[j], acc[i][j], 0, 0, 0);
    __syncthreads();
  }

  // epilogue: C/D layout col=lane&15, row=quad*4+reg
#pragma unroll
  for (int i = 0; i < 4; i++) {
    int gm0 = mbase + wave_m * 64 + i * 16 + quad * 4;
#pragma unroll
    for (int r = 0; r < 4; r++) {
      int gm = gm0 + r;
      if (gm >= M) continue;
#pragma unroll
      for (int j = 0; j < 4; j++) {
        int gn = nbase + wave_n * 64 + j * 16 + l15;
        float c = acc[i][j][r] + bias[gn];
        if (RES) c += res[(size_t)gm * N + gn];
        if (GELU_) c = 0.5f * c * (1.f + erff(c * 0.70710678118654752f));
        if (OBF) ((short*)Cout)[(size_t)gm * N + gn] = f2bf(c);
        else ((float*)Cout)[(size_t)gm * N + gn] = c;
      }
    }
  }
}

// ---------------------------------------------------------------------------
// fused attention: one wave per (b, h, q). qkv fp32 rows [q|k|v], o out bf16.
__global__ __launch_bounds__(64) void attn_kernel(
    const float* __restrict__ qkv, short* __restrict__ o) {
  int blk = blockIdx.x;
  int q_idx = blk % NTOK;
  int h = (blk / NTOK) % NH;
  int b = blk / (NTOK * NH);
  int lane = threadIdx.x;
  const float* base = qkv + (size_t)b * NTOK * 3 * D_;
  __shared__ float qs[64];
  __shared__ float sc[224];
  qs[lane] = base[(size_t)q_idx * 3 * D_ + h * HD + lane];
  __syncthreads();
  const float scale = 0.125f;
  for (int kk = lane; kk < NTOK; kk += 64) {
    const float* krow = base + (size_t)kk * 3 * D_ + D_ + h * HD;
    float s = 0.f;
#pragma unroll 8
    for (int i = 0; i < HD; i++) s += qs[i] * krow[i];
    sc[kk] = s * scale;
  }
  __syncthreads();
  float m = -1e30f;
  for (int kk = lane; kk < NTOK; kk += 64) m = fmaxf(m, sc[kk]);
#pragma unroll
  for (int off = 32; off; off >>= 1) m = fmaxf(m, __shfl_xor(m, off));
  float sum = 0.f;
  for (int kk = lane; kk < NTOK; kk += 64) {
    float e = __expf(sc[kk] - m);
    sc[kk] = e;
    sum += e;
  }
#pragma unroll
  for (int off = 32; off; off >>= 1) sum += __shfl_xor(sum, off);
  __syncthreads();
  float inv = 1.f / sum;
  float acc = 0.f;
  for (int kk = 0; kk < NTOK; kk++) {
    acc += sc[kk] * base[(size_t)kk * 3 * D_ + 2 * D_ + h * HD + lane];
  }
  o[((size_t)b * NTOK + q_idx) * D_ + h * HD + lane] = f2bf(acc * inv);
}

// ---------------------------------------------------------------------------
// head: out[b,j] = y[b,:] @ head_w[:,j] + head_b[j]; one wave per b.
__global__ __launch_bounds__(64) void head_kernel(
    const float* __restrict__ y, const float* __restrict__ hw,
    const float* __restrict__ hb, float* __restrict__ out) {
  int b = blockIdx.x;
  const float* yr = y + (size_t)b * D_;
  int lane = threadIdx.x;
  for (int j = 0; j < NCLS; j++) {
    float s = 0.f;
    for (int d = lane; d < D_; d += 64) s += yr[d] * hw[(size_t)d * NCLS + j];
#pragma unroll
    for (int off = 32; off; off >>= 1) s += __shfl_xor(s, off);
    if (lane == 0) out[b * NCLS + j] = s + hb[j];
  }
}

// ---------------------------------------------------------------------------
extern "C" void kernel_launch(void* const* d_in, const int* in_sizes, int n_in,
                              void* d_out, int out_size, void* d_ws, size_t ws_size,
                              hipStream_t stream) {
  const float* x        = (const float*)d_in[0];
  const float* conv_w   = (const float*)d_in[1];
  const float* conv_b   = (const float*)d_in[2];
  const float* cls_tok  = (const float*)d_in[3];
  const float* pos_emb  = (const float*)d_in[4];
  const float* ln1_g    = (const float*)d_in[5];
  const float* ln1_b    = (const float*)d_in[6];
  const float* qkv_w    = (const float*)d_in[7];
  const float* qkv_b    = (const float*)d_in[8];
  const float* proj_w   = (const float*)d_in[9];
  const float* proj_b   = (const float*)d_in[10];
  const float* ln2_g    = (const float*)d_in[11];
  const float* ln2_b    = (const float*)d_in[12];
  const float* fc1_w    = (const float*)d_in[13];
  const float* fc1_b    = (const float*)d_in[14];
  const float* fc2_w    = (const float*)d_in[15];
  const float* fc2_b    = (const float*)d_in[16];
  const float* norm_g   = (const float*)d_in[17];
  const float* norm_b   = (const float*)d_in[18];
  const float* head_w   = (const float*)d_in[19];
  const float* head_b   = (const float*)d_in[20];
  float* out = (float*)d_out;

  // ---- workspace layout (bytes) ----
  char* p = (char*)d_ws;
  float* tok    = (float*)p;                 p += (size_t)MTOK * D_ * 4;      // 19.4 MB
  short* y_bf   = (short*)p;                 p += (size_t)MPAD * D_ * 2;      // 9.8 MB
  short* o_bf   = (short*)p;                 p += (size_t)MPAD * D_ * 2;      // 9.8 MB
  short* h_bf   = (short*)p;                 p += (size_t)MPAD * DFF * 2;     // 39.3 MB
  short* wt_qkv = (short*)p;                 p += (size_t)D_ * 3 * D_ * 2;    // 3.5 MB
  short* wt_prj = (short*)p;                 p += (size_t)D_ * D_ * 2;        // 1.2 MB
  short* wt_fc1 = (short*)p;                 p += (size_t)D_ * DFF * 2;       // 4.7 MB
  short* wt_fc2 = (short*)p;                 p += (size_t)DFF * D_ * 2;       // 4.7 MB
  short* cw_bf  = (short*)p;                 p += (size_t)D_ * D_ * 2;        // 1.2 MB
  short* im_bf  = (short*)p;                 p += (size_t)MPAD * D_ * 2;      // 9.8 MB
  float* big1   = (float*)p;                 p += (size_t)MTOK * 3 * D_ * 4;  // 58.1 MB
  float* qkvb   = big1;                      // M x 2304 fp32 (layer loop)
  float* pout   = big1;                      // patch gemm out (pre-loop)
  float* yf     = (float*)(p);               // 32x768 fp32 final-LN out
  // yf fits: total above ~161.5 MB + 0.1

  // ---- patch embedding ----
  cvt_kernel<<<(D_ * D_ + 255) / 256, 256, 0, stream>>>(conv_w, cw_bf, D_ * D_);
  im2col_kernel<<<(MPATCH * D_ + 255) / 256, 256, 0, stream>>>(x, im_bf);
  cls_pos_kernel<<<(B_ * D_ + 255) / 256, 256, 0, stream>>>(cls_tok, pos_emb, tok);
  {
    dim3 g(D_ / 128, (MPATCH + 127) / 128);
    gemm_bf16_kernel<false, false, false><<<g, 256, 0, stream>>>(
        im_bf, cw_bf, conv_b, nullptr, pout, MPATCH, D_, D_);
  }
  patch_scatter_kernel<<<(MPATCH * D_ + 255) / 256, 256, 0, stream>>>(pout, pos_emb, tok);

  dim3 gQKV(3 * D_ / 128, (MTOK + 127) / 128);
  dim3 gPRJ(D_ / 128, (MTOK + 127) / 128);
  dim3 gFC1(DFF / 128, (MTOK + 127) / 128);
  dim3 gFC2(D_ / 128, (MTOK + 127) / 128);

  for (int l = 0; l < L_; l++) {
    const float* l1g = ln1_g + l * D_;
    const float* l1b = ln1_b + l * D_;
    const float* qw  = qkv_w + (size_t)l * D_ * 3 * D_;
    const float* qb  = qkv_b + (size_t)l * 3 * D_;
    const float* pw  = proj_w + (size_t)l * D_ * D_;
    const float* pb  = proj_b + (size_t)l * D_;
    const float* l2g = ln2_g + l * D_;
    const float* l2b = ln2_b + l * D_;
    const float* f1w = fc1_w + (size_t)l * D_ * DFF;
    const float* f1b = fc1_b + (size_t)l * DFF;
    const float* f2w = fc2_w + (size_t)l * DFF * D_;
    const float* f2b = fc2_b + (size_t)l * D_;

    // weight convert+transpose for this layer
    { dim3 g(3 * D_ / 32, D_ / 32);  wconv_kernel<<<g, 256, 0, stream>>>(qw, wt_qkv, D_, 3 * D_); }
    { dim3 g(D_ / 32, D_ / 32);      wconv_kernel<<<g, 256, 0, stream>>>(pw, wt_prj, D_, D_); }
    { dim3 g(DFF / 32, D_ / 32);     wconv_kernel<<<g, 256, 0, stream>>>(f1w, wt_fc1, D_, DFF); }
    { dim3 g(D_ / 32, DFF / 32);     wconv_kernel<<<g, 256, 0, stream>>>(f2w, wt_fc2, DFF, D_); }

    ln_kernel<true><<<MTOK, 256, 0, stream>>>(tok, y_bf, l1g, l1b, D_);
    gemm_bf16_kernel<false, false, false><<<gQKV, 256, 0, stream>>>(
        y_bf, wt_qkv, qb, nullptr, qkvb, MTOK, 3 * D_, D_);
    attn_kernel<<<B_ * NH * NTOK, 64, 0, stream>>>(qkvb, o_bf);
    gemm_bf16_kernel<false, true, false><<<gPRJ, 256, 0, stream>>>(
        o_bf, wt_prj, pb, tok, tok, MTOK, D_, D_);
    ln_kernel<true><<<MTOK, 256, 0, stream>>>(tok, y_bf, l2g, l2b, D_);
    gemm_bf16_kernel<true, false, true><<<gFC1, 256, 0, stream>>>(
        y_bf, wt_fc1, f1b, nullptr, h_bf, MTOK, DFF, D_);
    gemm_bf16_kernel<false, true, false><<<gFC2, 256, 0, stream>>>(
        h_bf, wt_fc2, f2b, tok, tok, MTOK, D_, DFF);
  }

  // final LN on token 0 of each batch, then head
  ln_kernel<false><<<B_, 256, 0, stream>>>(tok, yf, norm_g, norm_b, (long)NTOK * D_);
  head_kernel<<<B_, 64, 0, stream>>>(yf, head_w, head_b, out);
}

// Round 3
// 3798.468 us; speedup vs baseline: 7.1068x; 2.8813x over previous
//
#include <hip/hip_runtime.h>
#include <hip/hip_bf16.h>
#include <math.h>

#define B_      32
#define NTOK    197
#define NPATCH  196
#define D_      768
#define DFF     3072
#define L_      12
#define NH      12
#define HD      64
#define NCLS    5
#define MTOK    (B_ * NTOK)      // 6304
#define MPAD    6400
#define MPATCH  (B_ * NPATCH)    // 6272
#define KPAD    224              // keys padded to 14 tiles of 16
#define KS_STR  72               // Ks row stride (shorts), 144 B
#define VT_STR  232              // Vt/P row stride (shorts), 464 B

typedef __attribute__((ext_vector_type(8))) short short8;
typedef __attribute__((ext_vector_type(4))) float floatx4;

static __device__ inline short f2bf(float f) {
  __hip_bfloat16 h = __float2bfloat16(f);
  short s; __builtin_memcpy(&s, &h, 2); return s;
}

// ---------------------------------------------------------------------------
__global__ __launch_bounds__(256) void cls_pos_kernel(
    const float* __restrict__ cls, const float* __restrict__ pos,
    float* __restrict__ tok) {
  int i = blockIdx.x * 256 + threadIdx.x;
  if (i < B_ * D_) {
    int b = i / D_, d = i % D_;
    tok[(size_t)b * NTOK * D_ + d] = cls[d] + pos[d];
  }
}

// ---------------------------------------------------------------------------
__global__ __launch_bounds__(256) void cvt_kernel(
    const float* __restrict__ src, short* __restrict__ dst, int n) {
  int i = blockIdx.x * 256 + threadIdx.x;
  if (i < n) dst[i] = f2bf(src[i]);
}

// ---------------------------------------------------------------------------
// W[K,N] fp32 -> Wt[N,K] bf16, 32x32 LDS tiles.
__global__ __launch_bounds__(256) void wconv_kernel(
    const float* __restrict__ W, short* __restrict__ Wt, int K, int N) {
  __shared__ float t[32][33];
  int n0 = blockIdx.x * 32, k0 = blockIdx.y * 32;
  int tid = threadIdx.x;
#pragma unroll
  for (int q = 0; q < 4; q++) {
    int e = q * 256 + tid;
    int rk = e >> 5, cn = e & 31;
    t[rk][cn] = W[(size_t)(k0 + rk) * N + n0 + cn];
  }
  __syncthreads();
#pragma unroll
  for (int q = 0; q < 4; q++) {
    int e = q * 256 + tid;
    int rn = e >> 5, ck = e & 31;
    Wt[(size_t)(n0 + rn) * K + k0 + ck] = f2bf(t[ck][rn]);
  }
}

// ---------------------------------------------------------------------------
__global__ __launch_bounds__(256) void im2col_kernel(
    const float* __restrict__ x, short* __restrict__ Abf) {
  int i = blockIdx.x * 256 + threadIdx.x;
  if (i >= MPATCH * D_) return;
  int row = i / D_, col = i % D_;
  int b = row / NPATCH, n = row % NPATCH;
  int ph = n / 14, pw = n % 14;
  int c = col >> 8, r = col & 255;
  int kh = r >> 4, kw = r & 15;
  Abf[i] = f2bf(x[(((size_t)b * 3 + c) * 224 + (ph * 16 + kh)) * 224 + (pw * 16 + kw)]);
}

// ---------------------------------------------------------------------------
__global__ __launch_bounds__(256) void patch_scatter_kernel(
    const float* __restrict__ po, const float* __restrict__ pos,
    float* __restrict__ tok) {
  int i = blockIdx.x * 256 + threadIdx.x;
  if (i >= MPATCH * D_) return;
  int row = i / D_, col = i % D_;
  int b = row / NPATCH, n = row % NPATCH;
  tok[((size_t)b * NTOK + 1 + n) * D_ + col] = po[i] + pos[(size_t)(1 + n) * D_ + col];
}

// ---------------------------------------------------------------------------
template <bool OBF>
__global__ __launch_bounds__(256) void ln_kernel(
    const float* __restrict__ in, void* __restrict__ out,
    const float* __restrict__ g, const float* __restrict__ bt,
    long rs_in) {
  int row = blockIdx.x;
  const float* xr = in + (size_t)row * rs_in;
  int tid = threadIdx.x;
  float v0 = xr[tid], v1 = xr[tid + 256], v2 = xr[tid + 512];
  float s = v0 + v1 + v2;
#pragma unroll
  for (int off = 32; off; off >>= 1) s += __shfl_xor(s, off);
  __shared__ float red1[4], red2[4];
  int wid = tid >> 6, lane = tid & 63;
  if (lane == 0) red1[wid] = s;
  __syncthreads();
  float mean = (red1[0] + red1[1] + red1[2] + red1[3]) * (1.f / 768.f);
  float d0 = v0 - mean, d1 = v1 - mean, d2 = v2 - mean;
  float s2 = d0 * d0 + d1 * d1 + d2 * d2;
#pragma unroll
  for (int off = 32; off; off >>= 1) s2 += __shfl_xor(s2, off);
  if (lane == 0) red2[wid] = s2;
  __syncthreads();
  float var = (red2[0] + red2[1] + red2[2] + red2[3]) * (1.f / 768.f);
  float rstd = rsqrtf(var + 1e-5f);
  float o0 = d0 * rstd * g[tid]       + bt[tid];
  float o1 = d1 * rstd * g[tid + 256] + bt[tid + 256];
  float o2 = d2 * rstd * g[tid + 512] + bt[tid + 512];
  if (OBF) {
    short* yr = (short*)out + (size_t)row * D_;
    yr[tid] = f2bf(o0); yr[tid + 256] = f2bf(o1); yr[tid + 512] = f2bf(o2);
  } else {
    float* yr = (float*)out + (size_t)row * D_;
    yr[tid] = o0; yr[tid + 256] = o1; yr[tid + 512] = o2;
  }
}

// ---------------------------------------------------------------------------
// bf16 MFMA GEMM (m97 structure): C = A[M,K] @ Wt[N,K]^T + bias (+res)(gelu)
template <bool OBF, bool RES, bool GELU_>
__global__ __launch_bounds__(256) void gemm_bf16_kernel(
    const short* __restrict__ A, const short* __restrict__ Wt,
    const float* __restrict__ bias, const float* __restrict__ res,
    void* __restrict__ Cout, int M, int N, int K) {
  __shared__ short As[128 * 32];
  __shared__ short Bs[128 * 32];
  const int tid = threadIdx.x;
  const int lane = tid & 63;
  const int wid = tid >> 6;
  const int wave_m = wid >> 1, wave_n = wid & 1;
  const int mbase = blockIdx.y * 128;
  const int nbase = blockIdx.x * 128;

  const int lrow = lane >> 2;
  const int kbg = (lane & 3) ^ ((lane >> 3) & 3);
  const short* ga0 = A + (size_t)(mbase + wid * 32 + lrow) * K + kbg * 8;
  const short* ga1 = A + (size_t)(mbase + wid * 32 + 16 + lrow) * K + kbg * 8;
  const short* gb0 = Wt + (size_t)(nbase + wid * 32 + lrow) * K + kbg * 8;
  const short* gb1 = Wt + (size_t)(nbase + wid * 32 + 16 + lrow) * K + kbg * 8;
  typedef const __attribute__((address_space(1))) unsigned* gp_t;
  typedef __attribute__((address_space(3))) unsigned* lp_t;
  lp_t lA0 = (lp_t)(void*)(As + wid * 1024);
  lp_t lA1 = (lp_t)(void*)(As + wid * 1024 + 512);
  lp_t lB0 = (lp_t)(void*)(Bs + wid * 1024);
  lp_t lB1 = (lp_t)(void*)(Bs + wid * 1024 + 512);

  floatx4 zero = {0.f, 0.f, 0.f, 0.f};
  floatx4 acc[4][4];
#pragma unroll
  for (int i = 0; i < 4; i++)
#pragma unroll
    for (int j = 0; j < 4; j++) acc[i][j] = zero;

  const int quad = lane >> 4;
  const int l15 = lane & 15;
  const int s = quad ^ ((l15 >> 1) & 3);

  for (int k0 = 0; k0 < K; k0 += 32) {
    __builtin_amdgcn_global_load_lds((gp_t)(const void*)ga0, lA0, 16, 0, 0);
    __builtin_amdgcn_global_load_lds((gp_t)(const void*)ga1, lA1, 16, 0, 0);
    __builtin_amdgcn_global_load_lds((gp_t)(const void*)gb0, lB0, 16, 0, 0);
    __builtin_amdgcn_global_load_lds((gp_t)(const void*)gb1, lB1, 16, 0, 0);
    ga0 += 32; ga1 += 32; gb0 += 32; gb1 += 32;
    __syncthreads();
    short8 a[4], b[4];
#pragma unroll
    for (int i = 0; i < 4; i++) {
      int r = wave_m * 64 + i * 16 + l15;
      a[i] = *(const short8*)(As + r * 32 + s * 8);
      int c = wave_n * 64 + i * 16 + l15;
      b[i] = *(const short8*)(Bs + c * 32 + s * 8);
    }
#pragma unroll
    for (int i = 0; i < 4; i++)
#pragma unroll
      for (int j = 0; j < 4; j++)
        acc[i][j] = __builtin_amdgcn_mfma_f32_16x16x32_bf16(a[i], b[j], acc[i][j], 0, 0, 0);
    __syncthreads();
  }

#pragma unroll
  for (int i = 0; i < 4; i++) {
    int gm0 = mbase + wave_m * 64 + i * 16 + quad * 4;
#pragma unroll
    for (int r = 0; r < 4; r++) {
      int gm = gm0 + r;
      if (gm >= M) continue;
#pragma unroll
      for (int j = 0; j < 4; j++) {
        int gn = nbase + wave_n * 64 + j * 16 + l15;
        float c = acc[i][j][r] + bias[gn];
        if (RES) c += res[(size_t)gm * N + gn];
        if (GELU_) c = 0.5f * c * (1.f + erff(c * 0.70710678118654752f));
        if (OBF) ((short*)Cout)[(size_t)gm * N + gn] = f2bf(c);
        else ((float*)Cout)[(size_t)gm * N + gn] = c;
      }
    }
  }
}

// ---------------------------------------------------------------------------
// MFMA attention: one block (4 waves) per (b,h). qkv bf16 rows [q|k|v] x 768.
// K staged Ks[224][72], V staged transposed Vt[64][232], per-wave P[16][232].
__global__ __launch_bounds__(256) void attn_mfma_kernel(
    const short* __restrict__ qkv, short* __restrict__ o) {
  __shared__ short Ks[KPAD * KS_STR];        // 32.3 KB
  __shared__ short Vt[64 * VT_STR];          // 29.7 KB
  __shared__ short Pw[4 * 16 * VT_STR];      // 29.7 KB
  const int h = blockIdx.x % NH;
  const int b = blockIdx.x / NH;
  const int tid = threadIdx.x;
  const int lane = tid & 63, wid = tid >> 6;
  const size_t rowbase = (size_t)b * NTOK * (3 * D_);

  // stage K (row-major) and V (transposed)
  for (int it = 0; it < 7; it++) {
    int idx = it * 256 + tid;                // 1792 = 8 dblk * 224 keys
    int dblk = idx / KPAD, key = idx % KPAD;
    int krow = key < NTOK ? key : NTOK - 1;
    const short* src = qkv + rowbase + (size_t)krow * (3 * D_) + h * HD;
    short8 kv = *(const short8*)(src + D_ + dblk * 8);
    *(short8*)(Ks + key * KS_STR + dblk * 8) = kv;
    short8 vv = *(const short8*)(src + 2 * D_ + dblk * 8);
#pragma unroll
    for (int i = 0; i < 8; i++) Vt[(dblk * 8 + i) * VT_STR + key] = vv[i];
  }
  __syncthreads();

  const int quad = lane >> 4, l15 = lane & 15;
  short* P = Pw + wid * 16 * VT_STR;
  const floatx4 zero = {0.f, 0.f, 0.f, 0.f};

  for (int qt = wid; qt < 14; qt += 4) {
    int qrow = qt * 16 + l15;
    int qr = qrow < NTOK ? qrow : NTOK - 1;
    const short* qbase = qkv + rowbase + (size_t)qr * (3 * D_) + h * HD;
    short8 a0 = *(const short8*)(qbase + quad * 8);
    short8 a1 = *(const short8*)(qbase + 32 + quad * 8);

    // S = Q K^T, all 14 key tiles in registers
    floatx4 s[14];
#pragma unroll
    for (int kt = 0; kt < 14; kt++) {
      const short* kb = Ks + (kt * 16 + l15) * KS_STR;
      short8 b0 = *(const short8*)(kb + quad * 8);
      short8 b1 = *(const short8*)(kb + 32 + quad * 8);
      floatx4 c = __builtin_amdgcn_mfma_f32_16x16x32_bf16(a0, b0, zero, 0, 0, 0);
      s[kt] = __builtin_amdgcn_mfma_f32_16x16x32_bf16(a1, b1, c, 0, 0, 0);
    }
    // mask padded keys (key = kt*16 + l15)
#pragma unroll
    for (int kt = 0; kt < 14; kt++) {
      if (kt * 16 + l15 >= NTOK) {
#pragma unroll
        for (int r = 0; r < 4; r++) s[kt][r] = -1e30f;
      }
    }
    // rowwise max over keys (regs then 16-lane butterfly)
    float mx[4] = {-1e30f, -1e30f, -1e30f, -1e30f};
#pragma unroll
    for (int kt = 0; kt < 14; kt++)
#pragma unroll
      for (int r = 0; r < 4; r++) mx[r] = fmaxf(mx[r], s[kt][r]);
#pragma unroll
    for (int off = 1; off < 16; off <<= 1)
#pragma unroll
      for (int r = 0; r < 4; r++) mx[r] = fmaxf(mx[r], __shfl_xor(mx[r], off));
    // exp + store P (unnormalized) + row sum
    float lsum[4] = {0.f, 0.f, 0.f, 0.f};
#pragma unroll
    for (int kt = 0; kt < 14; kt++) {
#pragma unroll
      for (int r = 0; r < 4; r++) {
        float p = __expf(0.125f * (s[kt][r] - mx[r]));
        lsum[r] += p;
        P[(quad * 4 + r) * VT_STR + kt * 16 + l15] = f2bf(p);
      }
    }
#pragma unroll
    for (int off = 1; off < 16; off <<= 1)
#pragma unroll
      for (int r = 0; r < 4; r++) lsum[r] += __shfl_xor(lsum[r], off);
    float inv[4];
#pragma unroll
    for (int r = 0; r < 4; r++) inv[r] = 1.f / lsum[r];

    // O = P V  (K dim = 224 keys, 7 steps of 32)
    floatx4 oacc[4] = {zero, zero, zero, zero};
#pragma unroll
    for (int kk = 0; kk < 7; kk++) {
      short8 a = *(const short8*)(P + l15 * VT_STR + kk * 32 + quad * 8);
#pragma unroll
      for (int nt = 0; nt < 4; nt++) {
        short8 bv = *(const short8*)(Vt + (nt * 16 + l15) * VT_STR + kk * 32 + quad * 8);
        oacc[nt] = __builtin_amdgcn_mfma_f32_16x16x32_bf16(a, bv, oacc[nt], 0, 0, 0);
      }
    }
    // store O rows q = qt*16 + quad*4 + r, col d = nt*16 + l15
#pragma unroll
    for (int r = 0; r < 4; r++) {
      int q = qt * 16 + quad * 4 + r;
      if (q >= NTOK) continue;
      short* orow = o + ((size_t)(b * NTOK + q)) * D_ + h * HD;
#pragma unroll
      for (int nt = 0; nt < 4; nt++)
        orow[nt * 16 + l15] = f2bf(oacc[nt][r] * inv[r]);
    }
  }
}

// ---------------------------------------------------------------------------
__global__ __launch_bounds__(64) void head_kernel(
    const float* __restrict__ y, const float* __restrict__ hw,
    const float* __restrict__ hb, float* __restrict__ out) {
  int b = blockIdx.x;
  const float* yr = y + (size_t)b * D_;
  int lane = threadIdx.x;
  for (int j = 0; j < NCLS; j++) {
    float s = 0.f;
    for (int d = lane; d < D_; d += 64) s += yr[d] * hw[(size_t)d * NCLS + j];
#pragma unroll
    for (int off = 32; off; off >>= 1) s += __shfl_xor(s, off);
    if (lane == 0) out[b * NCLS + j] = s + hb[j];
  }
}

// ---------------------------------------------------------------------------
extern "C" void kernel_launch(void* const* d_in, const int* in_sizes, int n_in,
                              void* d_out, int out_size, void* d_ws, size_t ws_size,
                              hipStream_t stream) {
  const float* x        = (const float*)d_in[0];
  const float* conv_w   = (const float*)d_in[1];
  const float* conv_b   = (const float*)d_in[2];
  const float* cls_tok  = (const float*)d_in[3];
  const float* pos_emb  = (const float*)d_in[4];
  const float* ln1_g    = (const float*)d_in[5];
  const float* ln1_b    = (const float*)d_in[6];
  const float* qkv_w    = (const float*)d_in[7];
  const float* qkv_b    = (const float*)d_in[8];
  const float* proj_w   = (const float*)d_in[9];
  const float* proj_b   = (const float*)d_in[10];
  const float* ln2_g    = (const float*)d_in[11];
  const float* ln2_b    = (const float*)d_in[12];
  const float* fc1_w    = (const float*)d_in[13];
  const float* fc1_b    = (const float*)d_in[14];
  const float* fc2_w    = (const float*)d_in[15];
  const float* fc2_b    = (const float*)d_in[16];
  const float* norm_g   = (const float*)d_in[17];
  const float* norm_b   = (const float*)d_in[18];
  const float* head_w   = (const float*)d_in[19];
  const float* head_b   = (const float*)d_in[20];
  float* out = (float*)d_out;

  // ---- workspace layout ----
  char* p = (char*)d_ws;
  float* tok    = (float*)p;                 p += (size_t)MTOK * D_ * 4;
  short* y_bf   = (short*)p;                 p += (size_t)MPAD * D_ * 2;
  short* o_bf   = (short*)p;                 p += (size_t)MPAD * D_ * 2;
  short* h_bf   = (short*)p;                 p += (size_t)MPAD * DFF * 2;
  short* wt_qkv = (short*)p;                 p += (size_t)D_ * 3 * D_ * 2;
  short* wt_prj = (short*)p;                 p += (size_t)D_ * D_ * 2;
  short* wt_fc1 = (short*)p;                 p += (size_t)D_ * DFF * 2;
  short* wt_fc2 = (short*)p;                 p += (size_t)DFF * D_ * 2;
  short* cw_bf  = (short*)p;                 p += (size_t)D_ * D_ * 2;
  short* im_bf  = (short*)p;                 p += (size_t)MPAD * D_ * 2;
  float* big1   = (float*)p;                 p += (size_t)MTOK * 3 * D_ * 4;
  short* qkv_bf = (short*)big1;              // M x 2304 bf16 (layer loop)
  float* pout   = big1;                      // patch gemm out (pre-loop only)
  float* yf     = (float*)(p);               // 32x768 fp32 final-LN out

  // ---- patch embedding ----
  cvt_kernel<<<(D_ * D_ + 255) / 256, 256, 0, stream>>>(conv_w, cw_bf, D_ * D_);
  im2col_kernel<<<(MPATCH * D_ + 255) / 256, 256, 0, stream>>>(x, im_bf);
  cls_pos_kernel<<<(B_ * D_ + 255) / 256, 256, 0, stream>>>(cls_tok, pos_emb, tok);
  {
    dim3 g(D_ / 128, (MPATCH + 127) / 128);
    gemm_bf16_kernel<false, false, false><<<g, 256, 0, stream>>>(
        im_bf, cw_bf, conv_b, nullptr, pout, MPATCH, D_, D_);
  }
  patch_scatter_kernel<<<(MPATCH * D_ + 255) / 256, 256, 0, stream>>>(pout, pos_emb, tok);

  dim3 gQKV(3 * D_ / 128, (MTOK + 127) / 128);
  dim3 gPRJ(D_ / 128, (MTOK + 127) / 128);
  dim3 gFC1(DFF / 128, (MTOK + 127) / 128);
  dim3 gFC2(D_ / 128, (MTOK + 127) / 128);

  for (int l = 0; l < L_; l++) {
    const float* l1g = ln1_g + l * D_;
    const float* l1b = ln1_b + l * D_;
    const float* qw  = qkv_w + (size_t)l * D_ * 3 * D_;
    const float* qb  = qkv_b + (size_t)l * 3 * D_;
    const float* pw  = proj_w + (size_t)l * D_ * D_;
    const float* pb  = proj_b + (size_t)l * D_;
    const float* l2g = ln2_g + l * D_;
    const float* l2b = ln2_b + l * D_;
    const float* f1w = fc1_w + (size_t)l * D_ * DFF;
    const float* f1b = fc1_b + (size_t)l * DFF;
    const float* f2w = fc2_w + (size_t)l * DFF * D_;
    const float* f2b = fc2_b + (size_t)l * D_;

    { dim3 g(3 * D_ / 32, D_ / 32);  wconv_kernel<<<g, 256, 0, stream>>>(qw, wt_qkv, D_, 3 * D_); }
    { dim3 g(D_ / 32, D_ / 32);      wconv_kernel<<<g, 256, 0, stream>>>(pw, wt_prj, D_, D_); }
    { dim3 g(DFF / 32, D_ / 32);     wconv_kernel<<<g, 256, 0, stream>>>(f1w, wt_fc1, D_, DFF); }
    { dim3 g(D_ / 32, DFF / 32);     wconv_kernel<<<g, 256, 0, stream>>>(f2w, wt_fc2, DFF, D_); }

    ln_kernel<true><<<MTOK, 256, 0, stream>>>(tok, y_bf, l1g, l1b, D_);
    gemm_bf16_kernel<true, false, false><<<gQKV, 256, 0, stream>>>(
        y_bf, wt_qkv, qb, nullptr, qkv_bf, MTOK, 3 * D_, D_);
    attn_mfma_kernel<<<B_ * NH, 256, 0, stream>>>(qkv_bf, o_bf);
    gemm_bf16_kernel<false, true, false><<<gPRJ, 256, 0, stream>>>(
        o_bf, wt_prj, pb, tok, tok, MTOK, D_, D_);
    ln_kernel<true><<<MTOK, 256, 0, stream>>>(tok, y_bf, l2g, l2b, D_);
    gemm_bf16_kernel<true, false, true><<<gFC1, 256, 0, stream>>>(
        y_bf, wt_fc1, f1b, nullptr, h_bf, MTOK, DFF, D_);
    gemm_bf16_kernel<false, true, false><<<gFC2, 256, 0, stream>>>(
        h_bf, wt_fc2, f2b, tok, tok, MTOK, D_, DFF);
  }

  ln_kernel<false><<<B_, 256, 0, stream>>>(tok, yf, norm_g, norm_b, (long)NTOK * D_);
  head_kernel<<<B_, 64, 0, stream>>>(yf, head_w, head_b, out);
}

// Round 4
// 3685.993 us; speedup vs baseline: 7.3237x; 1.0305x over previous
//
#include <hip/hip_runtime.h>
#include <hip/hip_bf16.h>
#include <math.h>

#define B_      32
#define NTOK    197
#define NPATCH  196
#define D_      768
#define DFF     3072
#define L_      12
#define NH      12
#define HD      64
#define NCLS    5
#define MTOK    (B_ * NTOK)      // 6304
#define MPAD    6400
#define MPATCH  (B_ * NPATCH)    // 6272
#define KPAD    224
#define KS_STR  72
#define VT_STR  232

typedef __attribute__((ext_vector_type(8))) short short8;
typedef __attribute__((ext_vector_type(4))) float floatx4;

static __device__ inline short f2bf(float f) {
  __hip_bfloat16 h = __float2bfloat16(f);
  short s; __builtin_memcpy(&s, &h, 2); return s;
}

// ---------------------------------------------------------------------------
__global__ __launch_bounds__(256) void cls_pos_kernel(
    const float* __restrict__ cls, const float* __restrict__ pos,
    float* __restrict__ tok) {
  int i = blockIdx.x * 256 + threadIdx.x;
  if (i < B_ * D_) {
    int b = i / D_, d = i % D_;
    tok[(size_t)b * NTOK * D_ + d] = cls[d] + pos[d];
  }
}

// ---------------------------------------------------------------------------
__global__ __launch_bounds__(256) void cvt_kernel(
    const float* __restrict__ src, short* __restrict__ dst, int n) {
  int i = blockIdx.x * 256 + threadIdx.x;
  if (i < n) dst[i] = f2bf(src[i]);
}

// ---------------------------------------------------------------------------
// all 4 weight transposes of one layer in one dispatch. 32x32 tiles.
// tile counts: qkv 24x72=1728, proj 24x24=576, fc1 24x96=2304, fc2 96x24=2304
__global__ __launch_bounds__(256) void wconv_all_kernel(
    const float* __restrict__ qw, const float* __restrict__ pw,
    const float* __restrict__ f1w, const float* __restrict__ f2w,
    short* __restrict__ wq, short* __restrict__ wp,
    short* __restrict__ w1, short* __restrict__ w2) {
  int id = blockIdx.x;
  const float* W; short* Wt; int K, N, t;
  if (id < 1728)      { W = qw;  Wt = wq; K = 768;  N = 2304; t = id; }
  else if (id < 2304) { W = pw;  Wt = wp; K = 768;  N = 768;  t = id - 1728; }
  else if (id < 4608) { W = f1w; Wt = w1; K = 768;  N = 3072; t = id - 2304; }
  else                { W = f2w; Wt = w2; K = 3072; N = 768;  t = id - 4608; }
  int ntn = N >> 5;
  int k0 = (t / ntn) * 32, n0 = (t % ntn) * 32;
  __shared__ float tt[32][33];
  int tid = threadIdx.x;
#pragma unroll
  for (int q = 0; q < 4; q++) {
    int e = q * 256 + tid;
    int rk = e >> 5, cn = e & 31;
    tt[rk][cn] = W[(size_t)(k0 + rk) * N + n0 + cn];
  }
  __syncthreads();
#pragma unroll
  for (int q = 0; q < 4; q++) {
    int e = q * 256 + tid;
    int rn = e >> 5, ck = e & 31;
    Wt[(size_t)(n0 + rn) * K + k0 + ck] = f2bf(tt[ck][rn]);
  }
}

// ---------------------------------------------------------------------------
__global__ __launch_bounds__(256) void im2col_kernel(
    const float* __restrict__ x, short* __restrict__ Abf) {
  int i = blockIdx.x * 256 + threadIdx.x;
  if (i >= MPATCH * D_) return;
  int row = i / D_, col = i % D_;
  int b = row / NPATCH, n = row % NPATCH;
  int ph = n / 14, pw = n % 14;
  int c = col >> 8, r = col & 255;
  int kh = r >> 4, kw = r & 15;
  Abf[i] = f2bf(x[(((size_t)b * 3 + c) * 224 + (ph * 16 + kh)) * 224 + (pw * 16 + kw)]);
}

// ---------------------------------------------------------------------------
__global__ __launch_bounds__(256) void patch_scatter_kernel(
    const float* __restrict__ po, const float* __restrict__ pos,
    float* __restrict__ tok) {
  int i = blockIdx.x * 256 + threadIdx.x;
  if (i >= MPATCH * D_) return;
  int row = i / D_, col = i % D_;
  int b = row / NPATCH, n = row % NPATCH;
  tok[((size_t)b * NTOK + 1 + n) * D_ + col] = po[i] + pos[(size_t)(1 + n) * D_ + col];
}

// ---------------------------------------------------------------------------
template <bool OBF>
__global__ __launch_bounds__(256) void ln_kernel(
    const float* __restrict__ in, void* __restrict__ out,
    const float* __restrict__ g, const float* __restrict__ bt,
    long rs_in) {
  int row = blockIdx.x;
  const float* xr = in + (size_t)row * rs_in;
  int tid = threadIdx.x;
  float v0 = xr[tid], v1 = xr[tid + 256], v2 = xr[tid + 512];
  float s = v0 + v1 + v2;
#pragma unroll
  for (int off = 32; off; off >>= 1) s += __shfl_xor(s, off);
  __shared__ float red1[4], red2[4];
  int wid = tid >> 6, lane = tid & 63;
  if (lane == 0) red1[wid] = s;
  __syncthreads();
  float mean = (red1[0] + red1[1] + red1[2] + red1[3]) * (1.f / 768.f);
  float d0 = v0 - mean, d1 = v1 - mean, d2 = v2 - mean;
  float s2 = d0 * d0 + d1 * d1 + d2 * d2;
#pragma unroll
  for (int off = 32; off; off >>= 1) s2 += __shfl_xor(s2, off);
  if (lane == 0) red2[wid] = s2;
  __syncthreads();
  float var = (red2[0] + red2[1] + red2[2] + red2[3]) * (1.f / 768.f);
  float rstd = rsqrtf(var + 1e-5f);
  float o0 = d0 * rstd * g[tid]       + bt[tid];
  float o1 = d1 * rstd * g[tid + 256] + bt[tid + 256];
  float o2 = d2 * rstd * g[tid + 512] + bt[tid + 512];
  if (OBF) {
    short* yr = (short*)out + (size_t)row * D_;
    yr[tid] = f2bf(o0); yr[tid + 256] = f2bf(o1); yr[tid + 512] = f2bf(o2);
  } else {
    float* yr = (float*)out + (size_t)row * D_;
    yr[tid] = o0; yr[tid + 256] = o1; yr[tid + 512] = o2;
  }
}

// ---------------------------------------------------------------------------
// Double-buffered bf16 MFMA GEMM: C = A[M,K] @ Wt[N,K]^T + bias (+res)(gelu).
// BM=128: 4 waves (2x2), BM=64: 2 waves (1x2); each wave owns 64x64 via 4x4
// grid of 16x16x32 MFMA. One barrier per K-iter; global_load_lds for tile
// k+1 is issued right after the barrier and completes during compute(k).
template <int BM, bool OBF, bool RES, bool GELU_>
__global__ __launch_bounds__(256) void gemm_db_kernel(
    const short* __restrict__ A, const short* __restrict__ Wt,
    const float* __restrict__ bias, const float* __restrict__ res,
    void* __restrict__ Cout, int M, int N, int K) {
  constexpr int NBI = (BM == 128) ? 2 : 4;   // B-tile issues per wave
  __shared__ short As[2][BM * 32];
  __shared__ short Bs[2][128 * 32];
  const int tid = threadIdx.x;
  const int lane = tid & 63;
  const int wid = tid >> 6;
  const int wave_m = (BM == 128) ? (wid >> 1) : 0;
  const int wave_n = (BM == 128) ? (wid & 1) : wid;
  const int mbase = blockIdx.y * BM;
  const int nbase = blockIdx.x * 128;

  const int lrow = lane >> 2;
  const int kbg = (lane & 3) ^ ((lane >> 3) & 3);

  // A: wave wid stages rows [wid*32, wid*32+32), 2 chunks of 16 rows.
  const short* gA0 = A + (size_t)(mbase + wid * 32 + lrow) * K + kbg * 8;
  const short* gA1 = gA0 + 16 * (size_t)K;
  // B: BM=128 -> wave stages 32 rows (2 chunks); BM=64 -> 64 rows (4 chunks).
  const int brow0 = (BM == 128) ? (wid * 32) : (wid * 64);
  const short* gB[NBI];
  gB[0] = Wt + (size_t)(nbase + brow0 + lrow) * K + kbg * 8;
#pragma unroll
  for (int c = 1; c < NBI; c++) gB[c] = gB[0] + (size_t)c * 16 * K;

  typedef const __attribute__((address_space(1))) unsigned* gp_t;
  typedef __attribute__((address_space(3))) unsigned* lp_t;
  const int aoff = wid * 1024;
  const int boff = brow0 * 32;

  // prologue: stage tile 0 into buffer 0
  __builtin_amdgcn_global_load_lds((gp_t)(const void*)gA0, (lp_t)(void*)(&As[0][aoff]), 16, 0, 0);
  __builtin_amdgcn_global_load_lds((gp_t)(const void*)gA1, (lp_t)(void*)(&As[0][aoff + 512]), 16, 0, 0);
#pragma unroll
  for (int c = 0; c < NBI; c++)
    __builtin_amdgcn_global_load_lds((gp_t)(const void*)gB[c], (lp_t)(void*)(&Bs[0][boff + c * 512]), 16, 0, 0);

  floatx4 zero = {0.f, 0.f, 0.f, 0.f};
  floatx4 acc[4][4];
#pragma unroll
  for (int i = 0; i < 4; i++)
#pragma unroll
    for (int j = 0; j < 4; j++) acc[i][j] = zero;

  const int quad = lane >> 4;
  const int l15 = lane & 15;
  const int s = quad ^ ((l15 >> 1) & 3);

  const int niter = K >> 5;
  for (int it = 0; it < niter; it++) {
    const int cur = it & 1, nxt = cur ^ 1;
    __syncthreads();   // drains vmcnt: buf[cur] ready; lgkm: buf[nxt] reads done
    if (it + 1 < niter) {
      const int ks = (it + 1) << 5;
      __builtin_amdgcn_global_load_lds((gp_t)(const void*)(gA0 + ks), (lp_t)(void*)(&As[nxt][aoff]), 16, 0, 0);
      __builtin_amdgcn_global_load_lds((gp_t)(const void*)(gA1 + ks), (lp_t)(void*)(&As[nxt][aoff + 512]), 16, 0, 0);
#pragma unroll
      for (int c = 0; c < NBI; c++)
        __builtin_amdgcn_global_load_lds((gp_t)(const void*)(gB[c] + ks), (lp_t)(void*)(&Bs[nxt][boff + c * 512]), 16, 0, 0);
    }
    short8 a[4], b[4];
#pragma unroll
    for (int i = 0; i < 4; i++) {
      a[i] = *(const short8*)(&As[cur][(wave_m * 64 + i * 16 + l15) * 32 + s * 8]);
      b[i] = *(const short8*)(&Bs[cur][(wave_n * 64 + i * 16 + l15) * 32 + s * 8]);
    }
#pragma unroll
    for (int i = 0; i < 4; i++)
#pragma unroll
      for (int j = 0; j < 4; j++)
        acc[i][j] = __builtin_amdgcn_mfma_f32_16x16x32_bf16(a[i], b[j], acc[i][j], 0, 0, 0);
  }

  // epilogue: C/D layout col=lane&15, row=quad*4+reg
#pragma unroll
  for (int i = 0; i < 4; i++) {
    int gm0 = mbase + wave_m * 64 + i * 16 + quad * 4;
#pragma unroll
    for (int r = 0; r < 4; r++) {
      int gm = gm0 + r;
      if (gm >= M) continue;
#pragma unroll
      for (int j = 0; j < 4; j++) {
        int gn = nbase + wave_n * 64 + j * 16 + l15;
        float c = acc[i][j][r] + bias[gn];
        if (RES) c += res[(size_t)gm * N + gn];
        if (GELU_) c = 0.5f * c * (1.f + erff(c * 0.70710678118654752f));
        if (OBF) ((short*)Cout)[(size_t)gm * N + gn] = f2bf(c);
        else ((float*)Cout)[(size_t)gm * N + gn] = c;
      }
    }
  }
}

// ---------------------------------------------------------------------------
// MFMA attention: one block (4 waves) per (b,h).
__global__ __launch_bounds__(256) void attn_mfma_kernel(
    const short* __restrict__ qkv, short* __restrict__ o) {
  __shared__ short Ks[KPAD * KS_STR];
  __shared__ short Vt[64 * VT_STR];
  __shared__ short Pw[4 * 16 * VT_STR];
  const int h = blockIdx.x % NH;
  const int b = blockIdx.x / NH;
  const int tid = threadIdx.x;
  const int lane = tid & 63, wid = tid >> 6;
  const size_t rowbase = (size_t)b * NTOK * (3 * D_);

  for (int it = 0; it < 7; it++) {
    int idx = it * 256 + tid;
    int dblk = idx / KPAD, key = idx % KPAD;
    int krow = key < NTOK ? key : NTOK - 1;
    const short* src = qkv + rowbase + (size_t)krow * (3 * D_) + h * HD;
    short8 kv = *(const short8*)(src + D_ + dblk * 8);
    *(short8*)(Ks + key * KS_STR + dblk * 8) = kv;
    short8 vv = *(const short8*)(src + 2 * D_ + dblk * 8);
#pragma unroll
    for (int i = 0; i < 8; i++) Vt[(dblk * 8 + i) * VT_STR + key] = vv[i];
  }
  __syncthreads();

  const int quad = lane >> 4, l15 = lane & 15;
  short* P = Pw + wid * 16 * VT_STR;
  const floatx4 zero = {0.f, 0.f, 0.f, 0.f};

  for (int qt = wid; qt < 14; qt += 4) {
    int qrow = qt * 16 + l15;
    int qr = qrow < NTOK ? qrow : NTOK - 1;
    const short* qbase = qkv + rowbase + (size_t)qr * (3 * D_) + h * HD;
    short8 a0 = *(const short8*)(qbase + quad * 8);
    short8 a1 = *(const short8*)(qbase + 32 + quad * 8);

    floatx4 s[14];
#pragma unroll
    for (int kt = 0; kt < 14; kt++) {
      const short* kb = Ks + (kt * 16 + l15) * KS_STR;
      short8 b0 = *(const short8*)(kb + quad * 8);
      short8 b1 = *(const short8*)(kb + 32 + quad * 8);
      floatx4 c = __builtin_amdgcn_mfma_f32_16x16x32_bf16(a0, b0, zero, 0, 0, 0);
      s[kt] = __builtin_amdgcn_mfma_f32_16x16x32_bf16(a1, b1, c, 0, 0, 0);
    }
#pragma unroll
    for (int kt = 0; kt < 14; kt++) {
      if (kt * 16 + l15 >= NTOK) {
#pragma unroll
        for (int r = 0; r < 4; r++) s[kt][r] = -1e30f;
      }
    }
    float mx[4] = {-1e30f, -1e30f, -1e30f, -1e30f};
#pragma unroll
    for (int kt = 0; kt < 14; kt++)
#pragma unroll
      for (int r = 0; r < 4; r++) mx[r] = fmaxf(mx[r], s[kt][r]);
#pragma unroll
    for (int off = 1; off < 16; off <<= 1)
#pragma unroll
      for (int r = 0; r < 4; r++) mx[r] = fmaxf(mx[r], __shfl_xor(mx[r], off));
    float lsum[4] = {0.f, 0.f, 0.f, 0.f};
#pragma unroll
    for (int kt = 0; kt < 14; kt++) {
#pragma unroll
      for (int r = 0; r < 4; r++) {
        float p = __expf(0.125f * (s[kt][r] - mx[r]));
        lsum[r] += p;
        P[(quad * 4 + r) * VT_STR + kt * 16 + l15] = f2bf(p);
      }
    }
#pragma unroll
    for (int off = 1; off < 16; off <<= 1)
#pragma unroll
      for (int r = 0; r < 4; r++) lsum[r] += __shfl_xor(lsum[r], off);
    float inv[4];
#pragma unroll
    for (int r = 0; r < 4; r++) inv[r] = 1.f / lsum[r];

    floatx4 oacc[4] = {zero, zero, zero, zero};
#pragma unroll
    for (int kk = 0; kk < 7; kk++) {
      short8 a = *(const short8*)(P + l15 * VT_STR + kk * 32 + quad * 8);
#pragma unroll
      for (int nt = 0; nt < 4; nt++) {
        short8 bv = *(const short8*)(Vt + (nt * 16 + l15) * VT_STR + kk * 32 + quad * 8);
        oacc[nt] = __builtin_amdgcn_mfma_f32_16x16x32_bf16(a, bv, oacc[nt], 0, 0, 0);
      }
    }
#pragma unroll
    for (int r = 0; r < 4; r++) {
      int q = qt * 16 + quad * 4 + r;
      if (q >= NTOK) continue;
      short* orow = o + ((size_t)(b * NTOK + q)) * D_ + h * HD;
#pragma unroll
      for (int nt = 0; nt < 4; nt++)
        orow[nt * 16 + l15] = f2bf(oacc[nt][r] * inv[r]);
    }
  }
}

// ---------------------------------------------------------------------------
__global__ __launch_bounds__(64) void head_kernel(
    const float* __restrict__ y, const float* __restrict__ hw,
    const float* __restrict__ hb, float* __restrict__ out) {
  int b = blockIdx.x;
  const float* yr = y + (size_t)b * D_;
  int lane = threadIdx.x;
  for (int j = 0; j < NCLS; j++) {
    float s = 0.f;
    for (int d = lane; d < D_; d += 64) s += yr[d] * hw[(size_t)d * NCLS + j];
#pragma unroll
    for (int off = 32; off; off >>= 1) s += __shfl_xor(s, off);
    if (lane == 0) out[b * NCLS + j] = s + hb[j];
  }
}

// ---------------------------------------------------------------------------
extern "C" void kernel_launch(void* const* d_in, const int* in_sizes, int n_in,
                              void* d_out, int out_size, void* d_ws, size_t ws_size,
                              hipStream_t stream) {
  const float* x        = (const float*)d_in[0];
  const float* conv_w   = (const float*)d_in[1];
  const float* conv_b   = (const float*)d_in[2];
  const float* cls_tok  = (const float*)d_in[3];
  const float* pos_emb  = (const float*)d_in[4];
  const float* ln1_g    = (const float*)d_in[5];
  const float* ln1_b    = (const float*)d_in[6];
  const float* qkv_w    = (const float*)d_in[7];
  const float* qkv_b    = (const float*)d_in[8];
  const float* proj_w   = (const float*)d_in[9];
  const float* proj_b   = (const float*)d_in[10];
  const float* ln2_g    = (const float*)d_in[11];
  const float* ln2_b    = (const float*)d_in[12];
  const float* fc1_w    = (const float*)d_in[13];
  const float* fc1_b    = (const float*)d_in[14];
  const float* fc2_w    = (const float*)d_in[15];
  const float* fc2_b    = (const float*)d_in[16];
  const float* norm_g   = (const float*)d_in[17];
  const float* norm_b   = (const float*)d_in[18];
  const float* head_w   = (const float*)d_in[19];
  const float* head_b   = (const float*)d_in[20];
  float* out = (float*)d_out;

  // ---- workspace layout ----
  char* p = (char*)d_ws;
  float* tok    = (float*)p;                 p += (size_t)MTOK * D_ * 4;
  short* y_bf   = (short*)p;                 p += (size_t)MPAD * D_ * 2;
  short* o_bf   = (short*)p;                 p += (size_t)MPAD * D_ * 2;
  short* h_bf   = (short*)p;                 p += (size_t)MPAD * DFF * 2;
  short* wt_qkv = (short*)p;                 p += (size_t)D_ * 3 * D_ * 2;
  short* wt_prj = (short*)p;                 p += (size_t)D_ * D_ * 2;
  short* wt_fc1 = (short*)p;                 p += (size_t)D_ * DFF * 2;
  short* wt_fc2 = (short*)p;                 p += (size_t)DFF * D_ * 2;
  short* cw_bf  = (short*)p;                 p += (size_t)D_ * D_ * 2;
  short* im_bf  = (short*)p;                 p += (size_t)MPAD * D_ * 2;
  float* big1   = (float*)p;                 p += (size_t)MTOK * 3 * D_ * 4;
  short* qkv_bf = (short*)big1;              // M x 2304 bf16 (layer loop)
  float* pout   = big1;                      // patch gemm out (pre-loop only)
  float* yf     = (float*)(p);               // 32x768 fp32 final-LN out

  // ---- patch embedding ----
  cvt_kernel<<<(D_ * D_ + 255) / 256, 256, 0, stream>>>(conv_w, cw_bf, D_ * D_);
  im2col_kernel<<<(MPATCH * D_ + 255) / 256, 256, 0, stream>>>(x, im_bf);
  cls_pos_kernel<<<(B_ * D_ + 255) / 256, 256, 0, stream>>>(cls_tok, pos_emb, tok);
  {
    dim3 g(D_ / 128, MPATCH / 64);  // 6 x 98
    gemm_db_kernel<64, false, false, false><<<g, 128, 0, stream>>>(
        im_bf, cw_bf, conv_b, nullptr, pout, MPATCH, D_, D_);
  }
  patch_scatter_kernel<<<(MPATCH * D_ + 255) / 256, 256, 0, stream>>>(pout, pos_emb, tok);

  dim3 gQKV(3 * D_ / 128, (MTOK + 127) / 128);   // 18 x 50
  dim3 gPRJ(D_ / 128, (MTOK + 63) / 64);         // 6 x 99
  dim3 gFC1(DFF / 128, (MTOK + 127) / 128);      // 24 x 50
  dim3 gFC2(D_ / 128, (MTOK + 63) / 64);         // 6 x 99

  for (int l = 0; l < L_; l++) {
    const float* l1g = ln1_g + l * D_;
    const float* l1b = ln1_b + l * D_;
    const float* qw  = qkv_w + (size_t)l * D_ * 3 * D_;
    const float* qb  = qkv_b + (size_t)l * 3 * D_;
    const float* pw  = proj_w + (size_t)l * D_ * D_;
    const float* pb  = proj_b + (size_t)l * D_;
    const float* l2g = ln2_g + l * D_;
    const float* l2b = ln2_b + l * D_;
    const float* f1w = fc1_w + (size_t)l * D_ * DFF;
    const float* f1b = fc1_b + (size_t)l * DFF;
    const float* f2w = fc2_w + (size_t)l * DFF * D_;
    const float* f2b = fc2_b + (size_t)l * D_;

    wconv_all_kernel<<<6912, 256, 0, stream>>>(qw, pw, f1w, f2w,
                                               wt_qkv, wt_prj, wt_fc1, wt_fc2);

    ln_kernel<true><<<MTOK, 256, 0, stream>>>(tok, y_bf, l1g, l1b, D_);
    gemm_db_kernel<128, true, false, false><<<gQKV, 256, 0, stream>>>(
        y_bf, wt_qkv, qb, nullptr, qkv_bf, MTOK, 3 * D_, D_);
    attn_mfma_kernel<<<B_ * NH, 256, 0, stream>>>(qkv_bf, o_bf);
    gemm_db_kernel<64, false, true, false><<<gPRJ, 128, 0, stream>>>(
        o_bf, wt_prj, pb, tok, tok, MTOK, D_, D_);
    ln_kernel<true><<<MTOK, 256, 0, stream>>>(tok, y_bf, l2g, l2b, D_);
    gemm_db_kernel<128, true, false, true><<<gFC1, 256, 0, stream>>>(
        y_bf, wt_fc1, f1b, nullptr, h_bf, MTOK, DFF, D_);
    gemm_db_kernel<64, false, true, false><<<gFC2, 128, 0, stream>>>(
        h_bf, wt_fc2, f2b, tok, tok, MTOK, D_, DFF);
  }

  ln_kernel<false><<<B_, 256, 0, stream>>>(tok, yf, norm_g, norm_b, (long)NTOK * D_);
  head_kernel<<<B_, 64, 0, stream>>>(yf, head_w, head_b, out);
}